// Round 9
// baseline (161.244 us; speedup 1.0000x reference)
//
#include <hip/hip_runtime.h>

typedef short bf16x8 __attribute__((ext_vector_type(8)));
typedef float f32x4 __attribute__((ext_vector_type(4)));

constexpr int Bb = 8, Ntok = 2048, Cdim = 768, Ddim = 384, Mrows = 16384;

__device__ __forceinline__ void gload16(const void* g, void* l) {
    __builtin_amdgcn_global_load_lds(
        (const __attribute__((address_space(1))) unsigned int*)g,
        (__attribute__((address_space(3))) unsigned int*)l, 16, 0, 0);
}

// Hand-rolled RNE fp32->bf16 (finite inputs only)
__device__ __forceinline__ unsigned short f2bf(float x) {
    union { float f; unsigned u; } c; c.f = x;
    const unsigned r = c.u + 0x7fffu + ((c.u >> 16) & 1u);
    return (unsigned short)(r >> 16);
}
__device__ __forceinline__ float bf2f(unsigned short u) {
    union { unsigned u; float f; } c; c.u = (unsigned)u << 16;
    return c.f;
}
__device__ __forceinline__ uint4 cvt8(const float4 a, const float4 b) {
    union { unsigned short u[8]; uint4 q; } r;
    r.u[0] = f2bf(a.x); r.u[1] = f2bf(a.y); r.u[2] = f2bf(a.z); r.u[3] = f2bf(a.w);
    r.u[4] = f2bf(b.x); r.u[5] = f2bf(b.y); r.u[6] = f2bf(b.z); r.u[7] = f2bf(b.w);
    return r.q;
}

// acquire: all waves' staging landed -> begin reads. release: reads done.
#define ACQ()  do { __builtin_amdgcn_s_barrier(); asm volatile("" ::: "memory"); \
                    __builtin_amdgcn_sched_barrier(0); } while (0)
#define RELW() do { __builtin_amdgcn_sched_barrier(0); \
                    asm volatile("s_waitcnt lgkmcnt(0)" ::: "memory"); \
                    __builtin_amdgcn_s_barrier(); } while (0)
#define RELN() do { __builtin_amdgcn_sched_barrier(0); \
                    __builtin_amdgcn_s_barrier(); } while (0)

// T1 bijective XCD swizzle (bid->XCD assumed bid%8 round-robin).
// Requires (gridDim.y*gridDim.z)%8==0.
__device__ __forceinline__ void swz_xcd(int& bx, int& by, int& bz) {
    const int NN = gridDim.x, NY = gridDim.y;
    const int NP = NY * gridDim.z;
    const int lin = blockIdx.x + NN * (blockIdx.y + NY * blockIdx.z);
    const int x = lin & 7, g = lin >> 3;
    const int pan = x * (NP >> 3) + g / NN;
    bx = g % NN; by = pan % NY; bz = pan / NY;
}

// ---------------------------------------------------------------------------
__global__ __launch_bounds__(256) void cast_w(const float* __restrict__ s0, const float* __restrict__ s1,
                                              const float* __restrict__ s2, const float* __restrict__ s3,
                                              unsigned short* __restrict__ d0, unsigned short* __restrict__ d1,
                                              unsigned short* __restrict__ d2, unsigned short* __restrict__ d3) {
    constexpr int n8 = 294912 / 8;
    const int i = blockIdx.x * 256 + threadIdx.x;
    const int sel = i / n8, loc = i - sel * n8;
    const float* s = sel == 0 ? s0 : sel == 1 ? s1 : sel == 2 ? s2 : s3;
    unsigned short* d = sel == 0 ? d0 : sel == 1 ? d1 : sel == 2 ? d2 : d3;
    const float4* s4 = (const float4*)s;
    ((uint4*)d)[loc] = cvt8(s4[2 * loc], s4[2 * loc + 1]);
}

// ---------------------------------------------------------------------------
// bf16 MFMA NT GEMM, 128x128 tile, BK=32, 4 waves (2x2), 64x64/wave.
// 3-deep LDS pipeline (2-tile lookahead), counted vmcnt, raw barriers.
// AFP32: A fp32 reg-staged with TWO static reg sets (unroll-by-2), ds_write
//        one tile ahead. else: A+B via global_load_lds, 3-deep.
// vmcnt ledger (in-order retirement):
//   AFP32 per tile issue order [A regs x4, B glds x2]; steady wait vmcnt(12)
//     retires B(t) {left: A(t+1)4,B(t+1)2,A(t+2)4,B(t+2)2}; tails 6, 0.
//   non-AFP32 [A glds x2, B glds x2] -> steady vmcnt(8), tails 4, 0.
// OMODE 0 fp32 out; 1 bf16 out; 2 bf16 transposed per batch; 3 bf16 + BN stats.
// ---------------------------------------------------------------------------
template <int OMODE, bool SPLITK, bool AFP32>
__global__ __launch_bounds__(256) void gemm_bf16(
        const void* __restrict__ Abase_, long sA,
        const unsigned short* __restrict__ Bbase, long sB,
        const float* __restrict__ bias, const float* __restrict__ bias2, int Nsplit,
        void* __restrict__ Cbase, long sC,
        int M, int N, int K, float scale,
        float* __restrict__ psumG, float* __restrict__ psqG) {
    __shared__ __align__(16) char smem[49152];   // A bufs 3x8K | B bufs 3x8K

    int bxi, byi, bzi;
    swz_xcd(bxi, byi, bzi);

    const int tid  = threadIdx.x;
    const int lane = tid & 63;
    const int w    = tid >> 6;
    const int wm   = w >> 1, wn = w & 1;
    const int bm = byi * 128, bn = bxi * 128;
    const int zz = bzi;

    int zb, kStart, kEnd;
    if constexpr (SPLITK) {
        zb = zz >> 2;
        const int kl = K >> 2;
        kStart = (zz & 3) * kl;
        kEnd = kStart + kl;
    } else {
        zb = zz; kStart = 0; kEnd = K;
    }
    const int nt = (kEnd - kStart) >> 5;   // always even, >= 12

    const unsigned short* B = Bbase + (size_t)zb * sB;
    const float* Af = (const float*)Abase_ + (AFP32 ? (size_t)zb * sA : 0);
    const unsigned short* Ah = (const unsigned short*)Abase_ + (AFP32 ? 0 : (size_t)zb * sA);

    const int ldRow = tid >> 2;
    const int ldK   = (tid & 3) * 8;
    const unsigned ldsOff = tid * 16;
    const size_t aOff0 = (size_t)(bm + ldRow) * K + ldK;
    const size_t aOff1 = (size_t)(bm + 64 + ldRow) * K + ldK;
    const size_t bOff0 = (size_t)(bn + ldRow) * K + ldK;
    const size_t bOff1 = (size_t)(bn + 64 + ldRow) * K + ldK;

    f32x4 acc[4][4] = {};
    const int fr = lane & 15;
    const int fh = (lane >> 4) * 16;

    auto bufA = [&](int p) -> char* { return smem + p * 8192; };
    auto bufB = [&](int p) -> char* { return smem + 24576 + p * 8192; };

    auto stageB = [&](int p, int t) {
        const int k0 = kStart + t * 32;
        gload16(B + bOff0 + k0, bufB(p) + ldsOff);
        gload16(B + bOff1 + k0, bufB(p) + 4096 + ldsOff);
    };
    auto stageA_g = [&](int p, int t) {
        const int k0 = kStart + t * 32;
        gload16(Ah + aOff0 + k0, bufA(p) + ldsOff);
        gload16(Ah + aOff1 + k0, bufA(p) + 4096 + ldsOff);
    };

    float4 a00, a01, a02, a03, a10, a11, a12, a13;  // two static A reg sets
    auto loadA0 = [&](int t) {
        const int k0 = kStart + t * 32;
        a00 = *(const float4*)(Af + aOff0 + k0); a01 = *(const float4*)(Af + aOff0 + k0 + 4);
        a02 = *(const float4*)(Af + aOff1 + k0); a03 = *(const float4*)(Af + aOff1 + k0 + 4);
    };
    auto loadA1 = [&](int t) {
        const int k0 = kStart + t * 32;
        a10 = *(const float4*)(Af + aOff0 + k0); a11 = *(const float4*)(Af + aOff0 + k0 + 4);
        a12 = *(const float4*)(Af + aOff1 + k0); a13 = *(const float4*)(Af + aOff1 + k0 + 4);
    };
    auto writeA0 = [&](int p) {
        *(uint4*)(bufA(p) + ldsOff)        = cvt8(a00, a01);
        *(uint4*)(bufA(p) + 4096 + ldsOff) = cvt8(a02, a03);
    };
    auto writeA1 = [&](int p) {
        *(uint4*)(bufA(p) + ldsOff)        = cvt8(a10, a11);
        *(uint4*)(bufA(p) + 4096 + ldsOff) = cvt8(a12, a13);
    };

    auto compute = [&](int p) {
        const char* smA = bufA(p);
        const char* smB = bufB(p);
        bf16x8 fa[4], fb[4];
#pragma unroll
        for (int m = 0; m < 4; ++m)
            fa[m] = *(const bf16x8*)(smA + (wm * 64 + m * 16 + fr) * 64 + fh);
#pragma unroll
        for (int n = 0; n < 4; ++n)
            fb[n] = *(const bf16x8*)(smB + (wn * 64 + n * 16 + fr) * 64 + fh);
#pragma unroll
        for (int m = 0; m < 4; ++m)
#pragma unroll
            for (int n = 0; n < 4; ++n)
                acc[m][n] = __builtin_amdgcn_mfma_f32_16x16x32_bf16(fa[m], fb[n], acc[m][n], 0, 0, 0);
    };

    if constexpr (AFP32) {
        // prologue: tiles 0,1 in flight; tile0 A written to LDS
        loadA0(0); stageB(0, 0);
        loadA1(1); stageB(1, 1);
        writeA0(0);
        asm volatile("s_waitcnt lgkmcnt(0)" ::: "memory");
        int p = 0;
        for (int t = 0; t + 2 < nt; t += 2) {
            int p1 = p + 1; if (p1 == 3) p1 = 0;
            int p2 = p1 + 1; if (p2 == 3) p2 = 0;
            // even: tile t (buf p); prefetch tile t+2 (set0 -> buf p2 next iter)
            loadA0(t + 2); stageB(p2, t + 2);
            asm volatile("s_waitcnt vmcnt(12)" ::: "memory");
            ACQ();
            compute(p);
            writeA1(p1);                      // A(t+1) -> buf p1
            RELW();
            // odd: tile t+1 (buf p1); prefetch tile t+3 (exists: t <= nt-4)
            loadA1(t + 3); stageB(p, t + 3);
            asm volatile("s_waitcnt vmcnt(12)" ::: "memory");
            ACQ();
            compute(p1);
            writeA0(p2);                      // A(t+2) -> buf p2
            RELW();
            p = p2;
        }
        // tail: tiles nt-2 (buf p), nt-1 (buf p1)
        int p1 = p + 1; if (p1 == 3) p1 = 0;
        asm volatile("s_waitcnt vmcnt(6)" ::: "memory");
        ACQ();
        compute(p);
        writeA1(p1);                          // A(nt-1) -> buf p1
        RELW();
        asm volatile("s_waitcnt vmcnt(0)" ::: "memory");
        ACQ();
        compute(p1);
        RELN();
    } else {
        stageA_g(0, 0); stageB(0, 0);
        stageA_g(1, 1); stageB(1, 1);
        int p = 0;
        for (int t = 0; t < nt; ++t) {
            int p2 = p + 2; if (p2 >= 3) p2 -= 3;
            const bool m2 = (t + 2) < nt;
            if (m2) { stageA_g(p2, t + 2); stageB(p2, t + 2); }
            if (m2)                asm volatile("s_waitcnt vmcnt(8)" ::: "memory");
            else if (t + 1 < nt)   asm volatile("s_waitcnt vmcnt(4)" ::: "memory");
            else                   asm volatile("s_waitcnt vmcnt(0)" ::: "memory");
            ACQ();
            compute(p);
            RELN();
            p = p + 1 == 3 ? 0 : p + 1;
        }
    }

    const int r0 = (lane >> 4) * 4;
    const int cc = lane & 15;
    auto getbias = [&](int gcol) -> float {
        if (!bias) return 0.0f;
        return gcol < Nsplit ? bias[gcol] : bias2[gcol - Nsplit];
    };

    if constexpr (OMODE == 0) {
        float* C = (float*)Cbase + (size_t)(SPLITK ? zz : zb) * sC;
#pragma unroll
        for (int n = 0; n < 4; ++n) {
            const int col = bn + wn * 64 + n * 16 + cc;
            const float bv = getbias(col);
#pragma unroll
            for (int m = 0; m < 4; ++m)
#pragma unroll
                for (int j = 0; j < 4; ++j)
                    C[(size_t)(bm + wm * 64 + m * 16 + r0 + j) * N + col] = acc[m][n][j] + bv;
        }
    } else if constexpr (OMODE == 1) {
        unsigned short* C = (unsigned short*)Cbase + (size_t)zb * sC;
#pragma unroll
        for (int n = 0; n < 4; ++n) {
            const int col = bn + wn * 64 + n * 16 + cc;
            const float bv = getbias(col);
#pragma unroll
            for (int m = 0; m < 4; ++m)
#pragma unroll
                for (int j = 0; j < 4; ++j)
                    C[(size_t)(bm + wm * 64 + m * 16 + r0 + j) * N + col] =
                        f2bf(acc[m][n][j] * scale + bv);
        }
    } else if constexpr (OMODE == 2) {
        // LDS transpose then coalesced store to [b][col][token]
        unsigned short* T = (unsigned short*)smem;  // [128 cols][134 rows] bf16
#pragma unroll
        for (int n = 0; n < 4; ++n) {
            const int ccol = wn * 64 + n * 16 + cc;
            const float bv = getbias(bn + ccol);
#pragma unroll
            for (int m = 0; m < 4; ++m)
#pragma unroll
                for (int j = 0; j < 4; ++j)
                    T[ccol * 134 + (wm * 64 + m * 16 + r0 + j)] = f2bf(acc[m][n][j] + bv);
        }
        __syncthreads();
        const int b   = bm >> 11;
        const int bmb = bm & 2047;
        unsigned short* Co = (unsigned short*)Cbase + (size_t)b * N * Ntok;
#pragma unroll
        for (int i = 0; i < 32; ++i) {
            const int d = w * 32 + i;
            const unsigned v = *(const unsigned*)((const char*)smem + d * 268 + lane * 4);
            *(unsigned*)(Co + (size_t)(bn + d) * Ntok + bmb + lane * 2) = v;
        }
    } else {
        // OMODE 3: bf16 out + deterministic per-block column stats
        unsigned short* C = (unsigned short*)Cbase + (size_t)zb * sC;
        float colS[4], colQ[4];
#pragma unroll
        for (int n = 0; n < 4; ++n) {
            const int col = bn + wn * 64 + n * 16 + cc;
            const float bv = getbias(col);
            float s = 0.f, q = 0.f;
#pragma unroll
            for (int m = 0; m < 4; ++m)
#pragma unroll
                for (int j = 0; j < 4; ++j) {
                    const float v = acc[m][n][j] + bv;
                    C[(size_t)(bm + wm * 64 + m * 16 + r0 + j) * N + col] = f2bf(v);
                    s += v; q = fmaf(v, v, q);
                }
            s += __shfl_xor(s, 16); s += __shfl_xor(s, 32);
            q += __shfl_xor(q, 16); q += __shfl_xor(q, 32);
            colS[n] = s; colQ[n] = q;
        }
        float* sums = (float*)smem;   // [2 wm][128 cols]
        float* sqs  = sums + 256;
        if (lane < 16) {
#pragma unroll
            for (int n = 0; n < 4; ++n) {
                sums[wm * 128 + wn * 64 + n * 16 + cc] = colS[n];
                sqs [wm * 128 + wn * 64 + n * 16 + cc] = colQ[n];
            }
        }
        __syncthreads();
        if (tid < 128) {
            const int slot = zb * gridDim.y + byi;
            psumG[(size_t)slot * Cdim + bn + tid] = sums[tid] + sums[128 + tid];
            psqG [(size_t)slot * Cdim + bn + tid] = sqs[tid]  + sqs[128 + tid];
        }
    }
}

// ---------------------------------------------------------------------------
// Split-K reduce: M[b][d1][d2] = bf16( (1/2048) * sum_ks part[b*4+ks][d1][d2] )
// ---------------------------------------------------------------------------
__global__ __launch_bounds__(256) void reduce_mt(const float* __restrict__ part,
                                                 unsigned short* __restrict__ Mo) {
    const int i = blockIdx.x * 256 + threadIdx.x;
    const int e = i * 4;
    const int b = e / (Ddim * Ddim);
    const int r = e - b * (Ddim * Ddim);
    const float* base = part + (size_t)b * 4 * (Ddim * Ddim) + r;
    float4 s = *(const float4*)(base);
    const float4 s1 = *(const float4*)(base + 1 * Ddim * Ddim);
    const float4 s2 = *(const float4*)(base + 2 * Ddim * Ddim);
    const float4 s3 = *(const float4*)(base + 3 * Ddim * Ddim);
    s.x += s1.x + s2.x + s3.x; s.y += s1.y + s2.y + s3.y;
    s.z += s1.z + s2.z + s3.z; s.w += s1.w + s2.w + s3.w;
    constexpr float sc = 1.0f / (float)Ntok;
    union { unsigned short u[4]; uint2 q; } o;
    o.u[0] = f2bf(s.x * sc); o.u[1] = f2bf(s.y * sc);
    o.u[2] = f2bf(s.z * sc); o.u[3] = f2bf(s.w * sc);
    *(uint2*)(Mo + e) = o.q;
}

// ---------------------------------------------------------------------------
__global__ __launch_bounds__(256) void bn_finalize(const float* __restrict__ psum,
                                                   const float* __restrict__ psq,
                                                   const float* __restrict__ gamma,
                                                   const float* __restrict__ beta,
                                                   float* __restrict__ a,
                                                   float* __restrict__ bb) {
    const int c = blockIdx.x * 256 + threadIdx.x;
    if (c >= Cdim) return;
    float s = 0.f, q = 0.f;
    for (int b = 0; b < 128; ++b) { s += psum[(size_t)b * Cdim + c]; q += psq[(size_t)b * Cdim + c]; }
    const float mean = s * (1.0f / (float)Mrows);
    const float var  = fmaf(-mean, mean, q * (1.0f / (float)Mrows));
    const float inv  = rsqrtf(var + 1e-5f);
    const float gsc  = gamma[c] * inv;
    a[c]  = gsc;
    bb[c] = fmaf(-mean, gsc, beta[c]);
}

// out = a[c]*y + bb[c] + x_h ; y bf16, out fp32
__global__ __launch_bounds__(256) void bn_apply(const unsigned short* __restrict__ y,
                                                const float* __restrict__ xh,
                                                const float* __restrict__ a,
                                                const float* __restrict__ bb,
                                                float* __restrict__ outp) {
    const size_t i = (size_t)blockIdx.x * 256 + threadIdx.x;  // uint4 index = 8 bf16
    union { uint4 q; unsigned short u[8]; } v; v.q = ((const uint4*)y)[i];
    const int c8 = (int)(i % (Cdim / 8));
    const float4 A0 = ((const float4*)a)[c8 * 2],  A1 = ((const float4*)a)[c8 * 2 + 1];
    const float4 B0 = ((const float4*)bb)[c8 * 2], B1 = ((const float4*)bb)[c8 * 2 + 1];
    const float4 X0 = ((const float4*)xh)[i * 2],  X1 = ((const float4*)xh)[i * 2 + 1];
    float4 o0, o1;
    o0.x = fmaf(A0.x, bf2f(v.u[0]), B0.x) + X0.x;
    o0.y = fmaf(A0.y, bf2f(v.u[1]), B0.y) + X0.y;
    o0.z = fmaf(A0.z, bf2f(v.u[2]), B0.z) + X0.z;
    o0.w = fmaf(A0.w, bf2f(v.u[3]), B0.w) + X0.w;
    o1.x = fmaf(A1.x, bf2f(v.u[4]), B1.x) + X1.x;
    o1.y = fmaf(A1.y, bf2f(v.u[5]), B1.y) + X1.y;
    o1.z = fmaf(A1.z, bf2f(v.u[6]), B1.z) + X1.z;
    o1.w = fmaf(A1.w, bf2f(v.u[7]), B1.w) + X1.w;
    ((float4*)outp)[i * 2]     = o0;
    ((float4*)outp)[i * 2 + 1] = o1;
}

// ---------------------------------------------------------------------------
extern "C" void kernel_launch(void* const* d_in, const int* in_sizes, int n_in,
                              void* d_out, int out_size, void* d_ws, size_t ws_size,
                              hipStream_t stream) {
    const float* x_h   = (const float*)d_in[0];
    const float* x_l   = (const float*)d_in[1];
    const float* w_g   = (const float*)d_in[2];
    const float* b_g   = (const float*)d_in[3];
    const float* w_th  = (const float*)d_in[4];
    const float* b_th  = (const float*)d_in[5];
    const float* w_ph  = (const float*)d_in[6];
    const float* b_ph  = (const float*)d_in[7];
    const float* w_out = (const float*)d_in[8];
    const float* b_out = (const float*)d_in[9];
    const float* gamma = (const float*)d_in[10];
    const float* beta  = (const float*)d_in[11];
    float* out = (float*)d_out;

    char* p = (char*)d_ws;
    unsigned short* Scr   = (unsigned short*)p; p += (size_t)Mrows * Cdim * 2;  // split-K partials / Y bf16
    unsigned short* Wth16 = (unsigned short*)p; p += 294912 * 2;
    unsigned short* Wpg16 = (unsigned short*)p; p += 2 * 294912 * 2;            // [768][768]: w_phi | w_g
    unsigned short* Wout16= (unsigned short*)p; p += 294912 * 2;
    unsigned short* Tbuf  = (unsigned short*)p; p += (size_t)Mrows * Ddim * 2;  // theta bf16
    unsigned short* PGT   = (unsigned short*)p; p += (size_t)Mrows * Cdim * 2;  // [b][768][2048]: phi^T | g^T
    unsigned short* Mbuf  = (unsigned short*)p; p += (size_t)Bb * Ddim * Ddim * 2;
    unsigned short* QTbuf = (unsigned short*)p; p += (size_t)Bb * Cdim * Ddim * 2;
    float* psum = (float*)p; p += (size_t)128 * Cdim * 4;
    float* psq  = (float*)p; p += (size_t)128 * Cdim * 4;
    float* avec = (float*)p; p += Cdim * 4;
    float* bvec = (float*)p; p += Cdim * 4;
    float* part = (float*)Scr;
    unsigned short* Ybuf = Scr;

    dim3 blk(256);
    const int BIG = 1 << 30;

    cast_w<<<576, blk, 0, stream>>>(w_th, w_ph, w_g, w_out,
                                    Wth16, Wpg16, Wpg16 + 294912, Wout16);
    // theta = x_h * w_theta^T + b_theta (fp32 A inline-cast, bf16 out)
    gemm_bf16<1, false, true><<<dim3(3, 128, 1), blk, 0, stream>>>(
        x_h, 0, Wth16, 0, b_th, nullptr, BIG, Tbuf, 0, Mrows, Ddim, Cdim, 1.0f,
        nullptr, nullptr);
    // [phi | g] = x_l * [w_phi | w_g]^T + bias -> transposed [b][768][2048]
    gemm_bf16<2, false, true><<<dim3(6, 128, 1), blk, 0, stream>>>(
        x_l, 0, Wpg16, 0, b_ph, b_g, Ddim, PGT, 0, Mrows, 2 * Ddim, Cdim, 1.0f,
        nullptr, nullptr);
    // split-K partials: part[b*4+ks][d1][d2] = sum_{n slice} phi^T[d1][n] g^T[d2][n]
    gemm_bf16<0, true, false><<<dim3(3, 3, 32), blk, 0, stream>>>(
        PGT, (long)2 * Ddim * Ntok,
        PGT + (size_t)Ddim * Ntok, (long)2 * Ddim * Ntok, nullptr, nullptr, BIG,
        part, (long)Ddim * Ddim, Ddim, Ddim, Ntok, 1.0f, nullptr, nullptr);
    reduce_mt<<<1152, blk, 0, stream>>>(part, Mbuf);
    // QT[b][c][d1] = sum_d2 w_out[c][d2] * M[b][d1][d2]
    gemm_bf16<1, false, false><<<dim3(3, 6, 8), blk, 0, stream>>>(
        Wout16, 0, Mbuf, (long)Ddim * Ddim, nullptr, nullptr, BIG,
        QTbuf, (long)Cdim * Ddim, Cdim, Ddim, Ddim, 1.0f, nullptr, nullptr);
    // y = theta * QT^T + b_out -> bf16 Ybuf, fused BN column partials
    gemm_bf16<3, false, false><<<dim3(6, 16, 8), blk, 0, stream>>>(
        Tbuf, (long)Ntok * Ddim, QTbuf, (long)Cdim * Ddim, b_out, nullptr, BIG,
        Ybuf, (long)Ntok * Cdim, Ntok, Cdim, Ddim, 1.0f, psum, psq);
    // BN finalize + apply + residual
    bn_finalize<<<dim3(3), blk, 0, stream>>>(psum, psq, gamma, beta, avec, bvec);
    bn_apply<<<dim3(6144), blk, 0, stream>>>(Ybuf, x_h, avec, bvec, out);
}

// Round 10
// 153.193 us; speedup vs baseline: 1.0525x; 1.0525x over previous
//
#include <hip/hip_runtime.h>

typedef short bf16x8 __attribute__((ext_vector_type(8)));
typedef float f32x4 __attribute__((ext_vector_type(4)));

constexpr int Bb = 8, Ntok = 2048, Cdim = 768, Ddim = 384, Mrows = 16384;

__device__ __forceinline__ void gload16(const void* g, void* l) {
    __builtin_amdgcn_global_load_lds(
        (const __attribute__((address_space(1))) unsigned int*)g,
        (__attribute__((address_space(3))) unsigned int*)l, 16, 0, 0);
}

// Hand-rolled RNE fp32->bf16 (finite inputs only)
__device__ __forceinline__ unsigned short f2bf(float x) {
    union { float f; unsigned u; } c; c.f = x;
    const unsigned r = c.u + 0x7fffu + ((c.u >> 16) & 1u);
    return (unsigned short)(r >> 16);
}
__device__ __forceinline__ float bf2f(unsigned short u) {
    union { unsigned u; float f; } c; c.u = (unsigned)u << 16;
    return c.f;
}
__device__ __forceinline__ uint4 cvt8(const float4 a, const float4 b) {
    union { unsigned short u[8]; uint4 q; } r;
    r.u[0] = f2bf(a.x); r.u[1] = f2bf(a.y); r.u[2] = f2bf(a.z); r.u[3] = f2bf(a.w);
    r.u[4] = f2bf(b.x); r.u[5] = f2bf(b.y); r.u[6] = f2bf(b.z); r.u[7] = f2bf(b.w);
    return r.q;
}

__device__ __forceinline__ void fence_acq() {
    __builtin_amdgcn_s_barrier();
    asm volatile("" ::: "memory");
    __builtin_amdgcn_sched_barrier(0);
}
__device__ __forceinline__ void fence_rel() {
    __builtin_amdgcn_sched_barrier(0);
    asm volatile("s_waitcnt lgkmcnt(0)" ::: "memory");
    __builtin_amdgcn_s_barrier();
}

// T1 bijective XCD swizzle (bid->XCD assumed bid%8 round-robin).
// Requires (gridDim.y*gridDim.z)%8==0.
__device__ __forceinline__ void swz_xcd(int& bx, int& by, int& bz) {
    const int NN = gridDim.x, NY = gridDim.y;
    const int NP = NY * gridDim.z;
    const int lin = blockIdx.x + NN * (blockIdx.y + NY * blockIdx.z);
    const int x = lin & 7, g = lin >> 3;
    const int pan = x * (NP >> 3) + g / NN;
    bx = g % NN; by = pan % NY; bz = pan / NY;
}

// ---------------------------------------------------------------------------
__global__ __launch_bounds__(256) void cast_w(const float* __restrict__ s0, const float* __restrict__ s1,
                                              const float* __restrict__ s2, const float* __restrict__ s3,
                                              unsigned short* __restrict__ d0, unsigned short* __restrict__ d1,
                                              unsigned short* __restrict__ d2, unsigned short* __restrict__ d3) {
    constexpr int n8 = 294912 / 8;
    const int i = blockIdx.x * 256 + threadIdx.x;
    const int sel = i / n8, loc = i - sel * n8;
    const float* s = sel == 0 ? s0 : sel == 1 ? s1 : sel == 2 ? s2 : s3;
    unsigned short* d = sel == 0 ? d0 : sel == 1 ? d1 : sel == 2 ? d2 : d3;
    const float4* s4 = (const float4*)s;
    ((uint4*)d)[loc] = cvt8(s4[2 * loc], s4[2 * loc + 1]);
}

// ---------------------------------------------------------------------------
// bf16 MFMA NT GEMM, 128x128 tile, BK=32, 4 waves (2x2), 64x64/wave.
// 2-deep LDS (bufA[2]:0/8K, bufB[2]:16K/24K), counted vmcnt, raw barriers.
// AFP32: A fp32 reg-staged, TWO static reg sets, A-loads 2 tiles ahead,
//   B gload_lds 1 ahead, LDS write 1 ahead. Uniform vmcnt(6) ledger:
//   even iter t: issue A(t+2)x4, B(t+1)x2; queue [B(t)2,A(t+1)4 | A(t+2)4,B(t+1)2]
//   vmcnt(6) retires B(t)+A(t+1) -> compute(buf0) + writeA1(buf1) stall-free.
//   (odd iter symmetric). Tails: vmcnt(2) then vmcnt(0). nt must be even.
// non-AFP32 (unchanged from r8): A+B gload_lds 1 ahead, vmcnt(4)/0.
// OMODE 0 fp32 out; 1 bf16 out; 2 bf16 transposed per batch; 3 bf16 + BN stats.
// ---------------------------------------------------------------------------
template <int OMODE, bool SPLITK, bool AFP32>
__global__ __launch_bounds__(256) void gemm_bf16(
        const void* __restrict__ Abase_, long sA,
        const unsigned short* __restrict__ Bbase, long sB,
        const float* __restrict__ bias, const float* __restrict__ bias2, int Nsplit,
        void* __restrict__ Cbase, long sC,
        int M, int N, int K, float scale,
        float* __restrict__ psumG, float* __restrict__ psqG) {
    constexpr int SMEM_BYTES = (OMODE == 2) ? 34304 : 32768;
    __shared__ __align__(16) char smem[SMEM_BYTES];

    int bxi, byi, bzi;
    swz_xcd(bxi, byi, bzi);

    const int tid  = threadIdx.x;
    const int lane = tid & 63;
    const int w    = tid >> 6;
    const int wm   = w >> 1, wn = w & 1;
    const int bm = byi * 128, bn = bxi * 128;
    const int zz = bzi;

    int zb, kStart, kEnd;
    if constexpr (SPLITK) {
        zb = zz >> 2;
        const int kl = K >> 2;
        kStart = (zz & 3) * kl;
        kEnd = kStart + kl;
    } else {
        zb = zz; kStart = 0; kEnd = K;
    }

    const unsigned short* B = Bbase + (size_t)zb * sB;
    const float* Af = (const float*)Abase_ + (AFP32 ? (size_t)zb * sA : 0);
    const unsigned short* Ah = (const unsigned short*)Abase_ + (AFP32 ? 0 : (size_t)zb * sA);

    const int ldRow = tid >> 2;
    const int ldK   = (tid & 3) * 8;
    const unsigned ldsOff = tid * 16;
    const size_t aOff0 = (size_t)(bm + ldRow) * K + ldK;
    const size_t aOff1 = (size_t)(bm + 64 + ldRow) * K + ldK;
    const size_t bOff0 = (size_t)(bn + ldRow) * K + ldK;
    const size_t bOff1 = (size_t)(bn + 64 + ldRow) * K + ldK;

    f32x4 acc[4][4] = {};
    const int fr = lane & 15;
    const int fh = (lane >> 4) * 16;

    auto bufA = [&](int p) -> char* { return smem + p * 8192; };
    auto bufB = [&](int p) -> char* { return smem + 16384 + p * 8192; };

    auto stageB = [&](int p, int k0) {
        gload16(B + bOff0 + k0, bufB(p) + ldsOff);
        gload16(B + bOff1 + k0, bufB(p) + 4096 + ldsOff);
    };
    auto stageA_g = [&](int p, int k0) {
        gload16(Ah + aOff0 + k0, bufA(p) + ldsOff);
        gload16(Ah + aOff1 + k0, bufA(p) + 4096 + ldsOff);
    };

    float4 a00, a01, a02, a03, a10, a11, a12, a13;  // two static A reg sets
    auto loadA0 = [&](int k0) {
        a00 = *(const float4*)(Af + aOff0 + k0); a01 = *(const float4*)(Af + aOff0 + k0 + 4);
        a02 = *(const float4*)(Af + aOff1 + k0); a03 = *(const float4*)(Af + aOff1 + k0 + 4);
    };
    auto loadA1 = [&](int k0) {
        a10 = *(const float4*)(Af + aOff0 + k0); a11 = *(const float4*)(Af + aOff0 + k0 + 4);
        a12 = *(const float4*)(Af + aOff1 + k0); a13 = *(const float4*)(Af + aOff1 + k0 + 4);
    };
    auto writeA0 = [&](int p) {
        *(uint4*)(bufA(p) + ldsOff)        = cvt8(a00, a01);
        *(uint4*)(bufA(p) + 4096 + ldsOff) = cvt8(a02, a03);
    };
    auto writeA1 = [&](int p) {
        *(uint4*)(bufA(p) + ldsOff)        = cvt8(a10, a11);
        *(uint4*)(bufA(p) + 4096 + ldsOff) = cvt8(a12, a13);
    };

    auto compute = [&](int p) {
        const char* smA = bufA(p);
        const char* smB = bufB(p);
        bf16x8 fa[4], fb[4];
#pragma unroll
        for (int m = 0; m < 4; ++m)
            fa[m] = *(const bf16x8*)(smA + (wm * 64 + m * 16 + fr) * 64 + fh);
#pragma unroll
        for (int n = 0; n < 4; ++n)
            fb[n] = *(const bf16x8*)(smB + (wn * 64 + n * 16 + fr) * 64 + fh);
#pragma unroll
        for (int m = 0; m < 4; ++m)
#pragma unroll
            for (int n = 0; n < 4; ++n)
                acc[m][n] = __builtin_amdgcn_mfma_f32_16x16x32_bf16(fa[m], fb[n], acc[m][n], 0, 0, 0);
    };

    if constexpr (AFP32) {
        const int nt = (kEnd - kStart) >> 5;   // even (24 for all users)
        // prologue: A(0)->regs->buf0, B(0)->buf0, A(1)->regs
        loadA0(kStart);
        stageB(0, kStart);
        loadA1(kStart + 32);
        writeA0(0);                                     // implicit wait retires A(0)
        asm volatile("s_waitcnt lgkmcnt(0)" ::: "memory");  // A(0) ds_writes landed
        for (int t = 0; t + 2 < nt; t += 2) {
            // even tile t (buf0): prefetch A(t+2) regs, B(t+1)->buf1
            loadA0(kStart + (t + 2) * 32);
            stageB(1, kStart + (t + 1) * 32);
            asm volatile("s_waitcnt vmcnt(6)" ::: "memory");   // retires B(t), A(t+1)
            fence_acq();
            compute(0);
            writeA1(1);                                 // A(t+1) -> buf1
            fence_rel();
            // odd tile t+1 (buf1): prefetch A(t+3) regs, B(t+2)->buf0
            loadA1(kStart + (t + 3) * 32);
            stageB(0, kStart + (t + 2) * 32);
            asm volatile("s_waitcnt vmcnt(6)" ::: "memory");   // retires B(t+1), A(t+2)
            fence_acq();
            compute(1);
            writeA0(0);                                 // A(t+2) -> buf0
            fence_rel();
        }
        // tail: tiles nt-2 (buf0), nt-1 (buf1); outstanding: A(nt-1)4, B(nt-2)2
        stageB(1, kStart + (nt - 1) * 32);
        asm volatile("s_waitcnt vmcnt(2)" ::: "memory");       // retires A(nt-1), B(nt-2)
        fence_acq();
        compute(0);
        writeA1(1);
        fence_rel();
        asm volatile("s_waitcnt vmcnt(0)" ::: "memory");
        fence_acq();
        compute(1);
        __builtin_amdgcn_sched_barrier(0);
        __builtin_amdgcn_s_barrier();
    } else {
        const int nt = (kEnd - kStart) >> 5;
        stageA_g(0, kStart); stageB(0, kStart);
        int p = 0;
        for (int t = 0; t < nt; ++t, p ^= 1) {
            const bool more = (t + 1) < nt;
            if (more) { stageA_g(p ^ 1, kStart + (t + 1) * 32); stageB(p ^ 1, kStart + (t + 1) * 32); }
            if (more) asm volatile("s_waitcnt vmcnt(4)" ::: "memory");
            else      asm volatile("s_waitcnt vmcnt(0)" ::: "memory");
            fence_acq();
            compute(p);
            fence_rel();
        }
    }

    const int r0 = (lane >> 4) * 4;
    const int cc = lane & 15;
    auto getbias = [&](int gcol) -> float {
        if (!bias) return 0.0f;
        return gcol < Nsplit ? bias[gcol] : bias2[gcol - Nsplit];
    };

    if constexpr (OMODE == 0) {
        float* C = (float*)Cbase + (size_t)(SPLITK ? zz : zb) * sC;
#pragma unroll
        for (int n = 0; n < 4; ++n) {
            const int col = bn + wn * 64 + n * 16 + cc;
            const float bv = getbias(col);
#pragma unroll
            for (int m = 0; m < 4; ++m)
#pragma unroll
                for (int j = 0; j < 4; ++j)
                    C[(size_t)(bm + wm * 64 + m * 16 + r0 + j) * N + col] = acc[m][n][j] + bv;
        }
    } else if constexpr (OMODE == 1) {
        unsigned short* C = (unsigned short*)Cbase + (size_t)zb * sC;
#pragma unroll
        for (int n = 0; n < 4; ++n) {
            const int col = bn + wn * 64 + n * 16 + cc;
            const float bv = getbias(col);
#pragma unroll
            for (int m = 0; m < 4; ++m)
#pragma unroll
                for (int j = 0; j < 4; ++j)
                    C[(size_t)(bm + wm * 64 + m * 16 + r0 + j) * N + col] =
                        f2bf(acc[m][n][j] * scale + bv);
        }
    } else if constexpr (OMODE == 2) {
        // LDS transpose then coalesced store to [b][col][token]
        unsigned short* T = (unsigned short*)smem;  // [128 cols][134 rows] bf16
#pragma unroll
        for (int n = 0; n < 4; ++n) {
            const int ccol = wn * 64 + n * 16 + cc;
            const float bv = getbias(bn + ccol);
#pragma unroll
            for (int m = 0; m < 4; ++m)
#pragma unroll
                for (int j = 0; j < 4; ++j)
                    T[ccol * 134 + (wm * 64 + m * 16 + r0 + j)] = f2bf(acc[m][n][j] + bv);
        }
        __syncthreads();
        const int b   = bm >> 11;
        const int bmb = bm & 2047;
        unsigned short* Co = (unsigned short*)Cbase + (size_t)b * N * Ntok;
#pragma unroll
        for (int i = 0; i < 32; ++i) {
            const int d = w * 32 + i;
            const unsigned v = *(const unsigned*)((const char*)smem + d * 268 + lane * 4);
            *(unsigned*)(Co + (size_t)(bn + d) * Ntok + bmb + lane * 2) = v;
        }
    } else {
        // OMODE 3: bf16 out + deterministic per-block column stats
        unsigned short* C = (unsigned short*)Cbase + (size_t)zb * sC;
        float colS[4], colQ[4];
#pragma unroll
        for (int n = 0; n < 4; ++n) {
            const int col = bn + wn * 64 + n * 16 + cc;
            const float bv = getbias(col);
            float s = 0.f, q = 0.f;
#pragma unroll
            for (int m = 0; m < 4; ++m)
#pragma unroll
                for (int j = 0; j < 4; ++j) {
                    const float v = acc[m][n][j] + bv;
                    C[(size_t)(bm + wm * 64 + m * 16 + r0 + j) * N + col] = f2bf(v);
                    s += v; q = fmaf(v, v, q);
                }
            s += __shfl_xor(s, 16); s += __shfl_xor(s, 32);
            q += __shfl_xor(q, 16); q += __shfl_xor(q, 32);
            colS[n] = s; colQ[n] = q;
        }
        float* sums = (float*)smem;   // [2 wm][128 cols]
        float* sqs  = sums + 256;
        if (lane < 16) {
#pragma unroll
            for (int n = 0; n < 4; ++n) {
                sums[wm * 128 + wn * 64 + n * 16 + cc] = colS[n];
                sqs [wm * 128 + wn * 64 + n * 16 + cc] = colQ[n];
            }
        }
        __syncthreads();
        if (tid < 128) {
            const int slot = zb * gridDim.y + byi;
            psumG[(size_t)slot * Cdim + bn + tid] = sums[tid] + sums[128 + tid];
            psqG [(size_t)slot * Cdim + bn + tid] = sqs[tid]  + sqs[128 + tid];
        }
    }
}

// ---------------------------------------------------------------------------
// Split-K reduce: M[b][d1][d2] = bf16( (1/2048) * sum_ks part[b*4+ks][d1][d2] )
// ---------------------------------------------------------------------------
__global__ __launch_bounds__(256) void reduce_mt(const float* __restrict__ part,
                                                 unsigned short* __restrict__ Mo) {
    const int i = blockIdx.x * 256 + threadIdx.x;
    const int e = i * 4;
    const int b = e / (Ddim * Ddim);
    const int r = e - b * (Ddim * Ddim);
    const float* base = part + (size_t)b * 4 * (Ddim * Ddim) + r;
    float4 s = *(const float4*)(base);
    const float4 s1 = *(const float4*)(base + 1 * Ddim * Ddim);
    const float4 s2 = *(const float4*)(base + 2 * Ddim * Ddim);
    const float4 s3 = *(const float4*)(base + 3 * Ddim * Ddim);
    s.x += s1.x + s2.x + s3.x; s.y += s1.y + s2.y + s3.y;
    s.z += s1.z + s2.z + s3.z; s.w += s1.w + s2.w + s3.w;
    constexpr float sc = 1.0f / (float)Ntok;
    union { unsigned short u[4]; uint2 q; } o;
    o.u[0] = f2bf(s.x * sc); o.u[1] = f2bf(s.y * sc);
    o.u[2] = f2bf(s.z * sc); o.u[3] = f2bf(s.w * sc);
    *(uint2*)(Mo + e) = o.q;
}

// ---------------------------------------------------------------------------
__global__ __launch_bounds__(256) void bn_finalize(const float* __restrict__ psum,
                                                   const float* __restrict__ psq,
                                                   const float* __restrict__ gamma,
                                                   const float* __restrict__ beta,
                                                   float* __restrict__ a,
                                                   float* __restrict__ bb) {
    const int c = blockIdx.x * 256 + threadIdx.x;
    if (c >= Cdim) return;
    float s = 0.f, q = 0.f;
    for (int b = 0; b < 128; ++b) { s += psum[(size_t)b * Cdim + c]; q += psq[(size_t)b * Cdim + c]; }
    const float mean = s * (1.0f / (float)Mrows);
    const float var  = fmaf(-mean, mean, q * (1.0f / (float)Mrows));
    const float inv  = rsqrtf(var + 1e-5f);
    const float gsc  = gamma[c] * inv;
    a[c]  = gsc;
    bb[c] = fmaf(-mean, gsc, beta[c]);
}

// out = a[c]*y + bb[c] + x_h ; y bf16, out fp32
__global__ __launch_bounds__(256) void bn_apply(const unsigned short* __restrict__ y,
                                                const float* __restrict__ xh,
                                                const float* __restrict__ a,
                                                const float* __restrict__ bb,
                                                float* __restrict__ outp) {
    const size_t i = (size_t)blockIdx.x * 256 + threadIdx.x;  // uint4 index = 8 bf16
    union { uint4 q; unsigned short u[8]; } v; v.q = ((const uint4*)y)[i];
    const int c8 = (int)(i % (Cdim / 8));
    const float4 A0 = ((const float4*)a)[c8 * 2],  A1 = ((const float4*)a)[c8 * 2 + 1];
    const float4 B0 = ((const float4*)bb)[c8 * 2], B1 = ((const float4*)bb)[c8 * 2 + 1];
    const float4 X0 = ((const float4*)xh)[i * 2],  X1 = ((const float4*)xh)[i * 2 + 1];
    float4 o0, o1;
    o0.x = fmaf(A0.x, bf2f(v.u[0]), B0.x) + X0.x;
    o0.y = fmaf(A0.y, bf2f(v.u[1]), B0.y) + X0.y;
    o0.z = fmaf(A0.z, bf2f(v.u[2]), B0.z) + X0.z;
    o0.w = fmaf(A0.w, bf2f(v.u[3]), B0.w) + X0.w;
    o1.x = fmaf(A1.x, bf2f(v.u[4]), B1.x) + X1.x;
    o1.y = fmaf(A1.y, bf2f(v.u[5]), B1.y) + X1.y;
    o1.z = fmaf(A1.z, bf2f(v.u[6]), B1.z) + X1.z;
    o1.w = fmaf(A1.w, bf2f(v.u[7]), B1.w) + X1.w;
    ((float4*)outp)[i * 2]     = o0;
    ((float4*)outp)[i * 2 + 1] = o1;
}

// ---------------------------------------------------------------------------
extern "C" void kernel_launch(void* const* d_in, const int* in_sizes, int n_in,
                              void* d_out, int out_size, void* d_ws, size_t ws_size,
                              hipStream_t stream) {
    const float* x_h   = (const float*)d_in[0];
    const float* x_l   = (const float*)d_in[1];
    const float* w_g   = (const float*)d_in[2];
    const float* b_g   = (const float*)d_in[3];
    const float* w_th  = (const float*)d_in[4];
    const float* b_th  = (const float*)d_in[5];
    const float* w_ph  = (const float*)d_in[6];
    const float* b_ph  = (const float*)d_in[7];
    const float* w_out = (const float*)d_in[8];
    const float* b_out = (const float*)d_in[9];
    const float* gamma = (const float*)d_in[10];
    const float* beta  = (const float*)d_in[11];
    float* out = (float*)d_out;

    char* p = (char*)d_ws;
    unsigned short* Scr   = (unsigned short*)p; p += (size_t)Mrows * Cdim * 2;  // split-K partials / Y bf16
    unsigned short* Wth16 = (unsigned short*)p; p += 294912 * 2;
    unsigned short* Wpg16 = (unsigned short*)p; p += 2 * 294912 * 2;            // [768][768]: w_phi | w_g
    unsigned short* Wout16= (unsigned short*)p; p += 294912 * 2;
    unsigned short* Tbuf  = (unsigned short*)p; p += (size_t)Mrows * Ddim * 2;  // theta bf16
    unsigned short* PGT   = (unsigned short*)p; p += (size_t)Mrows * Cdim * 2;  // [b][768][2048]: phi^T | g^T
    unsigned short* Mbuf  = (unsigned short*)p; p += (size_t)Bb * Ddim * Ddim * 2;
    unsigned short* QTbuf = (unsigned short*)p; p += (size_t)Bb * Cdim * Ddim * 2;
    float* psum = (float*)p; p += (size_t)128 * Cdim * 4;
    float* psq  = (float*)p; p += (size_t)128 * Cdim * 4;
    float* avec = (float*)p; p += Cdim * 4;
    float* bvec = (float*)p; p += Cdim * 4;
    float* part = (float*)Scr;
    unsigned short* Ybuf = Scr;

    dim3 blk(256);
    const int BIG = 1 << 30;

    cast_w<<<576, blk, 0, stream>>>(w_th, w_ph, w_g, w_out,
                                    Wth16, Wpg16, Wpg16 + 294912, Wout16);
    // theta = x_h * w_theta^T + b_theta (fp32 A inline-cast, bf16 out)
    gemm_bf16<1, false, true><<<dim3(3, 128, 1), blk, 0, stream>>>(
        x_h, 0, Wth16, 0, b_th, nullptr, BIG, Tbuf, 0, Mrows, Ddim, Cdim, 1.0f,
        nullptr, nullptr);
    // [phi | g] = x_l * [w_phi | w_g]^T + bias -> transposed [b][768][2048]
    gemm_bf16<2, false, true><<<dim3(6, 128, 1), blk, 0, stream>>>(
        x_l, 0, Wpg16, 0, b_ph, b_g, Ddim, PGT, 0, Mrows, 2 * Ddim, Cdim, 1.0f,
        nullptr, nullptr);
    // split-K partials: part[b*4+ks][d1][d2] = sum_{n slice} phi^T[d1][n] g^T[d2][n]
    gemm_bf16<0, true, false><<<dim3(3, 3, 32), blk, 0, stream>>>(
        PGT, (long)2 * Ddim * Ntok,
        PGT + (size_t)Ddim * Ntok, (long)2 * Ddim * Ntok, nullptr, nullptr, BIG,
        part, (long)Ddim * Ddim, Ddim, Ddim, Ntok, 1.0f, nullptr, nullptr);
    reduce_mt<<<1152, blk, 0, stream>>>(part, Mbuf);
    // QT[b][c][d1] = sum_d2 w_out[c][d2] * M[b][d1][d2]
    gemm_bf16<1, false, false><<<dim3(3, 6, 8), blk, 0, stream>>>(
        Wout16, 0, Mbuf, (long)Ddim * Ddim, nullptr, nullptr, BIG,
        QTbuf, (long)Cdim * Ddim, Cdim, Ddim, Ddim, 1.0f, nullptr, nullptr);
    // y = theta * QT^T + b_out -> bf16 Ybuf, fused BN column partials
    gemm_bf16<3, false, false><<<dim3(6, 16, 8), blk, 0, stream>>>(
        Tbuf, (long)Ntok * Ddim, QTbuf, (long)Cdim * Ddim, b_out, nullptr, BIG,
        Ybuf, (long)Ntok * Cdim, Ntok, Cdim, Ddim, 1.0f, psum, psq);
    // BN finalize + apply + residual
    bn_finalize<<<dim3(3), blk, 0, stream>>>(psum, psq, gamma, beta, avec, bvec);
    bn_apply<<<dim3(6144), blk, 0, stream>>>(Ybuf, x_h, avec, bvec, out);
}

// Round 11
// 152.822 us; speedup vs baseline: 1.0551x; 1.0024x over previous
//
#include <hip/hip_runtime.h>

typedef short bf16x8 __attribute__((ext_vector_type(8)));
typedef float f32x4 __attribute__((ext_vector_type(4)));

constexpr int Bb = 8, Ntok = 2048, Cdim = 768, Ddim = 384, Mrows = 16384;

__device__ __forceinline__ void gload16(const void* g, void* l) {
    __builtin_amdgcn_global_load_lds(
        (const __attribute__((address_space(1))) unsigned int*)g,
        (__attribute__((address_space(3))) unsigned int*)l, 16, 0, 0);
}

// Hand-rolled RNE fp32->bf16 (finite inputs only)
__device__ __forceinline__ unsigned short f2bf(float x) {
    union { float f; unsigned u; } c; c.f = x;
    const unsigned r = c.u + 0x7fffu + ((c.u >> 16) & 1u);
    return (unsigned short)(r >> 16);
}
__device__ __forceinline__ float bf2f(unsigned short u) {
    union { unsigned u; float f; } c; c.u = (unsigned)u << 16;
    return c.f;
}
__device__ __forceinline__ uint4 cvt8(const float4 a, const float4 b) {
    union { unsigned short u[8]; uint4 q; } r;
    r.u[0] = f2bf(a.x); r.u[1] = f2bf(a.y); r.u[2] = f2bf(a.z); r.u[3] = f2bf(a.w);
    r.u[4] = f2bf(b.x); r.u[5] = f2bf(b.y); r.u[6] = f2bf(b.z); r.u[7] = f2bf(b.w);
    return r.q;
}

__device__ __forceinline__ void fence_acq() {
    __builtin_amdgcn_s_barrier();
    asm volatile("" ::: "memory");
    __builtin_amdgcn_sched_barrier(0);
}
__device__ __forceinline__ void fence_rel() {
    __builtin_amdgcn_sched_barrier(0);
    asm volatile("s_waitcnt lgkmcnt(0)" ::: "memory");
    __builtin_amdgcn_s_barrier();
}

// T1 bijective XCD swizzle (bid->XCD assumed bid%8 round-robin).
// Requires (gridDim.y*gridDim.z)%8==0.
__device__ __forceinline__ void swz_xcd(int& bx, int& by, int& bz) {
    const int NN = gridDim.x, NY = gridDim.y;
    const int NP = NY * gridDim.z;
    const int lin = blockIdx.x + NN * (blockIdx.y + NY * blockIdx.z);
    const int x = lin & 7, g = lin >> 3;
    const int pan = x * (NP >> 3) + g / NN;
    bx = g % NN; by = pan % NY; bz = pan / NY;
}

// ---------------------------------------------------------------------------
__global__ __launch_bounds__(256) void cast_w(const float* __restrict__ s0, const float* __restrict__ s1,
                                              const float* __restrict__ s2, const float* __restrict__ s3,
                                              unsigned short* __restrict__ d0, unsigned short* __restrict__ d1,
                                              unsigned short* __restrict__ d2, unsigned short* __restrict__ d3) {
    constexpr int n8 = 294912 / 8;
    const int i = blockIdx.x * 256 + threadIdx.x;
    const int sel = i / n8, loc = i - sel * n8;
    const float* s = sel == 0 ? s0 : sel == 1 ? s1 : sel == 2 ? s2 : s3;
    unsigned short* d = sel == 0 ? d0 : sel == 1 ? d1 : sel == 2 ? d2 : d3;
    const float4* s4 = (const float4*)s;
    ((uint4*)d)[loc] = cvt8(s4[2 * loc], s4[2 * loc + 1]);
}

// ---------------------------------------------------------------------------
// bf16 MFMA NT GEMM, 128x128 tile, BK=32, 4 waves (2x2), 64x64/wave.
// 2-deep LDS (bufA[2]:0/8K, bufB[2]:16K/24K), counted vmcnt, raw barriers.
// AFP32: A fp32 reg-staged, TWO static reg sets, A-loads 2 tiles ahead,
//   B gload_lds 1 ahead, LDS write 1 ahead. Uniform vmcnt(6) ledger:
//   even iter t: issue A(t+2)x4, B(t+1)x2; queue [B(t)2,A(t+1)4 | A(t+2)4,B(t+1)2]
//   vmcnt(6) retires B(t)+A(t+1) -> compute(buf0) + writeA1(buf1) stall-free.
//   (odd iter symmetric). Tails: vmcnt(2) then vmcnt(0). nt must be even.
// non-AFP32 (unchanged from r8): A+B gload_lds 1 ahead, vmcnt(4)/0.
// OMODE 0 fp32 out; 1 bf16 out; 2 bf16 transposed per batch; 3 bf16 + BN stats.
// ---------------------------------------------------------------------------
template <int OMODE, bool SPLITK, bool AFP32>
__global__ __launch_bounds__(256) void gemm_bf16(
        const void* __restrict__ Abase_, long sA,
        const unsigned short* __restrict__ Bbase, long sB,
        const float* __restrict__ bias, const float* __restrict__ bias2, int Nsplit,
        void* __restrict__ Cbase, long sC,
        int M, int N, int K, float scale,
        float* __restrict__ psumG, float* __restrict__ psqG) {
    constexpr int SMEM_BYTES = (OMODE == 2) ? 34304 : 32768;
    __shared__ __align__(16) char smem[SMEM_BYTES];

    int bxi, byi, bzi;
    swz_xcd(bxi, byi, bzi);

    const int tid  = threadIdx.x;
    const int lane = tid & 63;
    const int w    = tid >> 6;
    const int wm   = w >> 1, wn = w & 1;
    const int bm = byi * 128, bn = bxi * 128;
    const int zz = bzi;

    int zb, kStart, kEnd;
    if constexpr (SPLITK) {
        zb = zz >> 2;
        const int kl = K >> 2;
        kStart = (zz & 3) * kl;
        kEnd = kStart + kl;
    } else {
        zb = zz; kStart = 0; kEnd = K;
    }

    const unsigned short* B = Bbase + (size_t)zb * sB;
    const float* Af = (const float*)Abase_ + (AFP32 ? (size_t)zb * sA : 0);
    const unsigned short* Ah = (const unsigned short*)Abase_ + (AFP32 ? 0 : (size_t)zb * sA);

    const int ldRow = tid >> 2;
    const int ldK   = (tid & 3) * 8;
    const unsigned ldsOff = tid * 16;
    const size_t aOff0 = (size_t)(bm + ldRow) * K + ldK;
    const size_t aOff1 = (size_t)(bm + 64 + ldRow) * K + ldK;
    const size_t bOff0 = (size_t)(bn + ldRow) * K + ldK;
    const size_t bOff1 = (size_t)(bn + 64 + ldRow) * K + ldK;

    f32x4 acc[4][4] = {};
    const int fr = lane & 15;
    const int fh = (lane >> 4) * 16;

    auto bufA = [&](int p) -> char* { return smem + p * 8192; };
    auto bufB = [&](int p) -> char* { return smem + 16384 + p * 8192; };

    auto stageB = [&](int p, int k0) {
        gload16(B + bOff0 + k0, bufB(p) + ldsOff);
        gload16(B + bOff1 + k0, bufB(p) + 4096 + ldsOff);
    };
    auto stageA_g = [&](int p, int k0) {
        gload16(Ah + aOff0 + k0, bufA(p) + ldsOff);
        gload16(Ah + aOff1 + k0, bufA(p) + 4096 + ldsOff);
    };

    float4 a00, a01, a02, a03, a10, a11, a12, a13;  // two static A reg sets
    auto loadA0 = [&](int k0) {
        a00 = *(const float4*)(Af + aOff0 + k0); a01 = *(const float4*)(Af + aOff0 + k0 + 4);
        a02 = *(const float4*)(Af + aOff1 + k0); a03 = *(const float4*)(Af + aOff1 + k0 + 4);
    };
    auto loadA1 = [&](int k0) {
        a10 = *(const float4*)(Af + aOff0 + k0); a11 = *(const float4*)(Af + aOff0 + k0 + 4);
        a12 = *(const float4*)(Af + aOff1 + k0); a13 = *(const float4*)(Af + aOff1 + k0 + 4);
    };
    auto writeA0 = [&](int p) {
        *(uint4*)(bufA(p) + ldsOff)        = cvt8(a00, a01);
        *(uint4*)(bufA(p) + 4096 + ldsOff) = cvt8(a02, a03);
    };
    auto writeA1 = [&](int p) {
        *(uint4*)(bufA(p) + ldsOff)        = cvt8(a10, a11);
        *(uint4*)(bufA(p) + 4096 + ldsOff) = cvt8(a12, a13);
    };

    auto compute = [&](int p) {
        const char* smA = bufA(p);
        const char* smB = bufB(p);
        bf16x8 fa[4], fb[4];
#pragma unroll
        for (int m = 0; m < 4; ++m)
            fa[m] = *(const bf16x8*)(smA + (wm * 64 + m * 16 + fr) * 64 + fh);
#pragma unroll
        for (int n = 0; n < 4; ++n)
            fb[n] = *(const bf16x8*)(smB + (wn * 64 + n * 16 + fr) * 64 + fh);
#pragma unroll
        for (int m = 0; m < 4; ++m)
#pragma unroll
            for (int n = 0; n < 4; ++n)
                acc[m][n] = __builtin_amdgcn_mfma_f32_16x16x32_bf16(fa[m], fb[n], acc[m][n], 0, 0, 0);
    };

    if constexpr (AFP32) {
        const int nt = (kEnd - kStart) >> 5;   // even (24 for all users)
        // prologue: A(0)->regs->buf0, B(0)->buf0, A(1)->regs
        loadA0(kStart);
        stageB(0, kStart);
        loadA1(kStart + 32);
        writeA0(0);                                     // implicit wait retires A(0)
        asm volatile("s_waitcnt lgkmcnt(0)" ::: "memory");  // A(0) ds_writes landed
        for (int t = 0; t + 2 < nt; t += 2) {
            // even tile t (buf0): prefetch A(t+2) regs, B(t+1)->buf1
            loadA0(kStart + (t + 2) * 32);
            stageB(1, kStart + (t + 1) * 32);
            asm volatile("s_waitcnt vmcnt(6)" ::: "memory");   // retires B(t), A(t+1)
            fence_acq();
            compute(0);
            writeA1(1);                                 // A(t+1) -> buf1
            fence_rel();
            // odd tile t+1 (buf1): prefetch A(t+3) regs, B(t+2)->buf0
            loadA1(kStart + (t + 3) * 32);
            stageB(0, kStart + (t + 2) * 32);
            asm volatile("s_waitcnt vmcnt(6)" ::: "memory");   // retires B(t+1), A(t+2)
            fence_acq();
            compute(1);
            writeA0(0);                                 // A(t+2) -> buf0
            fence_rel();
        }
        // tail: tiles nt-2 (buf0), nt-1 (buf1); outstanding: A(nt-1)4, B(nt-2)2
        stageB(1, kStart + (nt - 1) * 32);
        asm volatile("s_waitcnt vmcnt(2)" ::: "memory");       // retires A(nt-1), B(nt-2)
        fence_acq();
        compute(0);
        writeA1(1);
        fence_rel();
        asm volatile("s_waitcnt vmcnt(0)" ::: "memory");
        fence_acq();
        compute(1);
        __builtin_amdgcn_sched_barrier(0);
        __builtin_amdgcn_s_barrier();
    } else {
        const int nt = (kEnd - kStart) >> 5;
        stageA_g(0, kStart); stageB(0, kStart);
        int p = 0;
        for (int t = 0; t < nt; ++t, p ^= 1) {
            const bool more = (t + 1) < nt;
            if (more) { stageA_g(p ^ 1, kStart + (t + 1) * 32); stageB(p ^ 1, kStart + (t + 1) * 32); }
            if (more) asm volatile("s_waitcnt vmcnt(4)" ::: "memory");
            else      asm volatile("s_waitcnt vmcnt(0)" ::: "memory");
            fence_acq();
            compute(p);
            fence_rel();
        }
    }

    const int r0 = (lane >> 4) * 4;
    const int cc = lane & 15;
    auto getbias = [&](int gcol) -> float {
        if (!bias) return 0.0f;
        return gcol < Nsplit ? bias[gcol] : bias2[gcol - Nsplit];
    };

    if constexpr (OMODE == 0) {
        float* C = (float*)Cbase + (size_t)(SPLITK ? zz : zb) * sC;
#pragma unroll
        for (int n = 0; n < 4; ++n) {
            const int col = bn + wn * 64 + n * 16 + cc;
            const float bv = getbias(col);
#pragma unroll
            for (int m = 0; m < 4; ++m)
#pragma unroll
                for (int j = 0; j < 4; ++j)
                    C[(size_t)(bm + wm * 64 + m * 16 + r0 + j) * N + col] = acc[m][n][j] + bv;
        }
    } else if constexpr (OMODE == 1) {
        unsigned short* C = (unsigned short*)Cbase + (size_t)zb * sC;
#pragma unroll
        for (int n = 0; n < 4; ++n) {
            const int col = bn + wn * 64 + n * 16 + cc;
            const float bv = getbias(col);
#pragma unroll
            for (int m = 0; m < 4; ++m)
#pragma unroll
                for (int j = 0; j < 4; ++j)
                    C[(size_t)(bm + wm * 64 + m * 16 + r0 + j) * N + col] =
                        f2bf(acc[m][n][j] * scale + bv);
        }
    } else if constexpr (OMODE == 2) {
        // LDS transpose then coalesced store to [b][col][token]
        unsigned short* T = (unsigned short*)smem;  // [128 cols][134 rows] bf16
#pragma unroll
        for (int n = 0; n < 4; ++n) {
            const int ccol = wn * 64 + n * 16 + cc;
            const float bv = getbias(bn + ccol);
#pragma unroll
            for (int m = 0; m < 4; ++m)
#pragma unroll
                for (int j = 0; j < 4; ++j)
                    T[ccol * 134 + (wm * 64 + m * 16 + r0 + j)] = f2bf(acc[m][n][j] + bv);
        }
        __syncthreads();
        const int b   = bm >> 11;
        const int bmb = bm & 2047;
        unsigned short* Co = (unsigned short*)Cbase + (size_t)b * N * Ntok;
#pragma unroll
        for (int i = 0; i < 32; ++i) {
            const int d = w * 32 + i;
            const unsigned v = *(const unsigned*)((const char*)smem + d * 268 + lane * 4);
            *(unsigned*)(Co + (size_t)(bn + d) * Ntok + bmb + lane * 2) = v;
        }
    } else {
        // OMODE 3: bf16 out + deterministic per-block column stats
        unsigned short* C = (unsigned short*)Cbase + (size_t)zb * sC;
        float colS[4], colQ[4];
#pragma unroll
        for (int n = 0; n < 4; ++n) {
            const int col = bn + wn * 64 + n * 16 + cc;
            const float bv = getbias(col);
            float s = 0.f, q = 0.f;
#pragma unroll
            for (int m = 0; m < 4; ++m)
#pragma unroll
                for (int j = 0; j < 4; ++j) {
                    const float v = acc[m][n][j] + bv;
                    C[(size_t)(bm + wm * 64 + m * 16 + r0 + j) * N + col] = f2bf(v);
                    s += v; q = fmaf(v, v, q);
                }
            s += __shfl_xor(s, 16); s += __shfl_xor(s, 32);
            q += __shfl_xor(q, 16); q += __shfl_xor(q, 32);
            colS[n] = s; colQ[n] = q;
        }
        float* sums = (float*)smem;   // [2 wm][128 cols]
        float* sqs  = sums + 256;
        if (lane < 16) {
#pragma unroll
            for (int n = 0; n < 4; ++n) {
                sums[wm * 128 + wn * 64 + n * 16 + cc] = colS[n];
                sqs [wm * 128 + wn * 64 + n * 16 + cc] = colQ[n];
            }
        }
        __syncthreads();
        if (tid < 128) {
            const int slot = zb * gridDim.y + byi;
            psumG[(size_t)slot * Cdim + bn + tid] = sums[tid] + sums[128 + tid];
            psqG [(size_t)slot * Cdim + bn + tid] = sqs[tid]  + sqs[128 + tid];
        }
    }
}

// ---------------------------------------------------------------------------
// Split-K reduce: M[b][d1][d2] = bf16( (1/2048) * sum_ks part[b*4+ks][d1][d2] )
// ---------------------------------------------------------------------------
__global__ __launch_bounds__(256) void reduce_mt(const float* __restrict__ part,
                                                 unsigned short* __restrict__ Mo) {
    const int i = blockIdx.x * 256 + threadIdx.x;
    const int e = i * 4;
    const int b = e / (Ddim * Ddim);
    const int r = e - b * (Ddim * Ddim);
    const float* base = part + (size_t)b * 4 * (Ddim * Ddim) + r;
    float4 s = *(const float4*)(base);
    const float4 s1 = *(const float4*)(base + 1 * Ddim * Ddim);
    const float4 s2 = *(const float4*)(base + 2 * Ddim * Ddim);
    const float4 s3 = *(const float4*)(base + 3 * Ddim * Ddim);
    s.x += s1.x + s2.x + s3.x; s.y += s1.y + s2.y + s3.y;
    s.z += s1.z + s2.z + s3.z; s.w += s1.w + s2.w + s3.w;
    constexpr float sc = 1.0f / (float)Ntok;
    union { unsigned short u[4]; uint2 q; } o;
    o.u[0] = f2bf(s.x * sc); o.u[1] = f2bf(s.y * sc);
    o.u[2] = f2bf(s.z * sc); o.u[3] = f2bf(s.w * sc);
    *(uint2*)(Mo + e) = o.q;
}

// ---------------------------------------------------------------------------
__global__ __launch_bounds__(256) void bn_finalize(const float* __restrict__ psum,
                                                   const float* __restrict__ psq,
                                                   const float* __restrict__ gamma,
                                                   const float* __restrict__ beta,
                                                   float* __restrict__ a,
                                                   float* __restrict__ bb) {
    const int c = blockIdx.x * 256 + threadIdx.x;
    if (c >= Cdim) return;
    float s = 0.f, q = 0.f;
    for (int b = 0; b < 128; ++b) { s += psum[(size_t)b * Cdim + c]; q += psq[(size_t)b * Cdim + c]; }
    const float mean = s * (1.0f / (float)Mrows);
    const float var  = fmaf(-mean, mean, q * (1.0f / (float)Mrows));
    const float inv  = rsqrtf(var + 1e-5f);
    const float gsc  = gamma[c] * inv;
    a[c]  = gsc;
    bb[c] = fmaf(-mean, gsc, beta[c]);
}

// out = a[c]*y + bb[c] + x_h ; y bf16, out fp32
__global__ __launch_bounds__(256) void bn_apply(const unsigned short* __restrict__ y,
                                                const float* __restrict__ xh,
                                                const float* __restrict__ a,
                                                const float* __restrict__ bb,
                                                float* __restrict__ outp) {
    const size_t i = (size_t)blockIdx.x * 256 + threadIdx.x;  // uint4 index = 8 bf16
    union { uint4 q; unsigned short u[8]; } v; v.q = ((const uint4*)y)[i];
    const int c8 = (int)(i % (Cdim / 8));
    const float4 A0 = ((const float4*)a)[c8 * 2],  A1 = ((const float4*)a)[c8 * 2 + 1];
    const float4 B0 = ((const float4*)bb)[c8 * 2], B1 = ((const float4*)bb)[c8 * 2 + 1];
    const float4 X0 = ((const float4*)xh)[i * 2],  X1 = ((const float4*)xh)[i * 2 + 1];
    float4 o0, o1;
    o0.x = fmaf(A0.x, bf2f(v.u[0]), B0.x) + X0.x;
    o0.y = fmaf(A0.y, bf2f(v.u[1]), B0.y) + X0.y;
    o0.z = fmaf(A0.z, bf2f(v.u[2]), B0.z) + X0.z;
    o0.w = fmaf(A0.w, bf2f(v.u[3]), B0.w) + X0.w;
    o1.x = fmaf(A1.x, bf2f(v.u[4]), B1.x) + X1.x;
    o1.y = fmaf(A1.y, bf2f(v.u[5]), B1.y) + X1.y;
    o1.z = fmaf(A1.z, bf2f(v.u[6]), B1.z) + X1.z;
    o1.w = fmaf(A1.w, bf2f(v.u[7]), B1.w) + X1.w;
    ((float4*)outp)[i * 2]     = o0;
    ((float4*)outp)[i * 2 + 1] = o1;
}

// ---------------------------------------------------------------------------
extern "C" void kernel_launch(void* const* d_in, const int* in_sizes, int n_in,
                              void* d_out, int out_size, void* d_ws, size_t ws_size,
                              hipStream_t stream) {
    const float* x_h   = (const float*)d_in[0];
    const float* x_l   = (const float*)d_in[1];
    const float* w_g   = (const float*)d_in[2];
    const float* b_g   = (const float*)d_in[3];
    const float* w_th  = (const float*)d_in[4];
    const float* b_th  = (const float*)d_in[5];
    const float* w_ph  = (const float*)d_in[6];
    const float* b_ph  = (const float*)d_in[7];
    const float* w_out = (const float*)d_in[8];
    const float* b_out = (const float*)d_in[9];
    const float* gamma = (const float*)d_in[10];
    const float* beta  = (const float*)d_in[11];
    float* out = (float*)d_out;

    char* p = (char*)d_ws;
    unsigned short* Scr   = (unsigned short*)p; p += (size_t)Mrows * Cdim * 2;  // split-K partials / Y bf16
    unsigned short* Wth16 = (unsigned short*)p; p += 294912 * 2;
    unsigned short* Wpg16 = (unsigned short*)p; p += 2 * 294912 * 2;            // [768][768]: w_phi | w_g
    unsigned short* Wout16= (unsigned short*)p; p += 294912 * 2;
    unsigned short* Tbuf  = (unsigned short*)p; p += (size_t)Mrows * Ddim * 2;  // theta bf16
    unsigned short* PGT   = (unsigned short*)p; p += (size_t)Mrows * Cdim * 2;  // [b][768][2048]: phi^T | g^T
    unsigned short* Mbuf  = (unsigned short*)p; p += (size_t)Bb * Ddim * Ddim * 2;
    unsigned short* QTbuf = (unsigned short*)p; p += (size_t)Bb * Cdim * Ddim * 2;
    float* psum = (float*)p; p += (size_t)128 * Cdim * 4;
    float* psq  = (float*)p; p += (size_t)128 * Cdim * 4;
    float* avec = (float*)p; p += Cdim * 4;
    float* bvec = (float*)p; p += Cdim * 4;
    float* part = (float*)Scr;
    unsigned short* Ybuf = Scr;

    dim3 blk(256);
    const int BIG = 1 << 30;

    cast_w<<<576, blk, 0, stream>>>(w_th, w_ph, w_g, w_out,
                                    Wth16, Wpg16, Wpg16 + 294912, Wout16);
    // theta = x_h * w_theta^T + b_theta (fp32 A inline-cast, bf16 out)
    gemm_bf16<1, false, true><<<dim3(3, 128, 1), blk, 0, stream>>>(
        x_h, 0, Wth16, 0, b_th, nullptr, BIG, Tbuf, 0, Mrows, Ddim, Cdim, 1.0f,
        nullptr, nullptr);
    // [phi | g] = x_l * [w_phi | w_g]^T + bias -> transposed [b][768][2048]
    gemm_bf16<2, false, true><<<dim3(6, 128, 1), blk, 0, stream>>>(
        x_l, 0, Wpg16, 0, b_ph, b_g, Ddim, PGT, 0, Mrows, 2 * Ddim, Cdim, 1.0f,
        nullptr, nullptr);
    // split-K partials: part[b*4+ks][d1][d2] = sum_{n slice} phi^T[d1][n] g^T[d2][n]
    gemm_bf16<0, true, false><<<dim3(3, 3, 32), blk, 0, stream>>>(
        PGT, (long)2 * Ddim * Ntok,
        PGT + (size_t)Ddim * Ntok, (long)2 * Ddim * Ntok, nullptr, nullptr, BIG,
        part, (long)Ddim * Ddim, Ddim, Ddim, Ntok, 1.0f, nullptr, nullptr);
    reduce_mt<<<1152, blk, 0, stream>>>(part, Mbuf);
    // QT[b][c][d1] = sum_d2 w_out[c][d2] * M[b][d1][d2]
    gemm_bf16<1, false, false><<<dim3(3, 6, 8), blk, 0, stream>>>(
        Wout16, 0, Mbuf, (long)Ddim * Ddim, nullptr, nullptr, BIG,
        QTbuf, (long)Cdim * Ddim, Cdim, Ddim, Ddim, 1.0f, nullptr, nullptr);
    // y = theta * QT^T + b_out -> bf16 Ybuf, fused BN column partials
    gemm_bf16<3, false, false><<<dim3(6, 16, 8), blk, 0, stream>>>(
        Tbuf, (long)Ntok * Ddim, QTbuf, (long)Cdim * Ddim, b_out, nullptr, BIG,
        Ybuf, (long)Ntok * Cdim, Ntok, Cdim, Ddim, 1.0f, psum, psq);
    // BN finalize + apply + residual
    bn_finalize<<<dim3(3), blk, 0, stream>>>(psum, psq, gamma, beta, avec, bvec);
    bn_apply<<<dim3(6144), blk, 0, stream>>>(Ybuf, x_h, avec, bvec, out);
}

// Round 12
// 145.548 us; speedup vs baseline: 1.1078x; 1.0500x over previous
//
#include <hip/hip_runtime.h>

typedef short bf16x8 __attribute__((ext_vector_type(8)));
typedef float f32x4 __attribute__((ext_vector_type(4)));

constexpr int Bb = 8, Ntok = 2048, Cdim = 768, Ddim = 384, Mrows = 16384;

__device__ __forceinline__ void gload16(const void* g, void* l) {
    __builtin_amdgcn_global_load_lds(
        (const __attribute__((address_space(1))) unsigned int*)g,
        (__attribute__((address_space(3))) unsigned int*)l, 16, 0, 0);
}

// Hand-rolled RNE fp32->bf16 (finite inputs only)
__device__ __forceinline__ unsigned short f2bf(float x) {
    union { float f; unsigned u; } c; c.f = x;
    const unsigned r = c.u + 0x7fffu + ((c.u >> 16) & 1u);
    return (unsigned short)(r >> 16);
}
__device__ __forceinline__ float bf2f(unsigned short u) {
    union { unsigned u; float f; } c; c.u = (unsigned)u << 16;
    return c.f;
}
__device__ __forceinline__ uint4 cvt8(const float4 a, const float4 b) {
    union { unsigned short u[8]; uint4 q; } r;
    r.u[0] = f2bf(a.x); r.u[1] = f2bf(a.y); r.u[2] = f2bf(a.z); r.u[3] = f2bf(a.w);
    r.u[4] = f2bf(b.x); r.u[5] = f2bf(b.y); r.u[6] = f2bf(b.z); r.u[7] = f2bf(b.w);
    return r.q;
}

// Counted-vmcnt barrier discipline, NO sched_barrier(0) (m141: order-pinning
// defeats the compiler's ds_read<->MFMA interleave). Each wave waits its OWN
// staging loads (vmcnt) before the barrier -> after barrier all waves' LDS
// writes are visible. "memory" clobbers pin memory ops only; VALU/MFMA float.
#define ACQ()  do { asm volatile("" ::: "memory"); __builtin_amdgcn_s_barrier(); \
                    asm volatile("" ::: "memory"); } while (0)
#define REL_W() do { asm volatile("s_waitcnt lgkmcnt(0)" ::: "memory"); \
                     __builtin_amdgcn_s_barrier(); asm volatile("" ::: "memory"); } while (0)
#define REL_N() do { asm volatile("" ::: "memory"); __builtin_amdgcn_s_barrier(); \
                     asm volatile("" ::: "memory"); } while (0)

// T1 bijective XCD swizzle (bid->XCD assumed bid%8 round-robin).
// Requires (gridDim.y*gridDim.z)%8==0.
__device__ __forceinline__ void swz_xcd(int& bx, int& by, int& bz) {
    const int NN = gridDim.x, NY = gridDim.y;
    const int NP = NY * gridDim.z;
    const int lin = blockIdx.x + NN * (blockIdx.y + NY * blockIdx.z);
    const int x = lin & 7, g = lin >> 3;
    const int pan = x * (NP >> 3) + g / NN;
    bx = g % NN; by = pan % NY; bz = pan / NY;
}

// ---------------------------------------------------------------------------
__global__ __launch_bounds__(256) void cast_w(const float* __restrict__ s0, const float* __restrict__ s1,
                                              const float* __restrict__ s2, const float* __restrict__ s3,
                                              unsigned short* __restrict__ d0, unsigned short* __restrict__ d1,
                                              unsigned short* __restrict__ d2, unsigned short* __restrict__ d3) {
    constexpr int n8 = 294912 / 8;
    const int i = blockIdx.x * 256 + threadIdx.x;
    const int sel = i / n8, loc = i - sel * n8;
    const float* s = sel == 0 ? s0 : sel == 1 ? s1 : sel == 2 ? s2 : s3;
    unsigned short* d = sel == 0 ? d0 : sel == 1 ? d1 : sel == 2 ? d2 : d3;
    const float4* s4 = (const float4*)s;
    ((uint4*)d)[loc] = cvt8(s4[2 * loc], s4[2 * loc + 1]);
}

// ---------------------------------------------------------------------------
// bf16 MFMA NT GEMM, 128x128 tile, BK=32, 4 waves (2x2), 64x64/wave.
// 2-deep LDS (bufA[2]:0/8K, bufB[2]:16K/24K), counted vmcnt + raw barriers,
// compiler free to interleave (no sched_barrier).
// AFP32: A fp32 -> regs (1 tile ahead) -> cvt+ds_write AFTER compute (implicit
//   reg-dependency wait lands post-MFMA = one compute phase of hiding).
//   vmcnt ledger: issue [A(t+1)x4, B(t+1)x2] -> outstanding B(t)2+6=8;
//   vmcnt(6) retires B(t) only. writeA implicit wait -> vmcnt(2). Tail 0.
// non-AFP32: A+B gload_lds 1 ahead; vmcnt(4) retires tile t's 4. Tail 0.
// OMODE 0 fp32 out; 1 bf16 out; 2 bf16 transposed per batch; 3 bf16 + BN stats.
// ---------------------------------------------------------------------------
template <int OMODE, bool SPLITK, bool AFP32>
__global__ __launch_bounds__(256) void gemm_bf16(
        const void* __restrict__ Abase_, long sA,
        const unsigned short* __restrict__ Bbase, long sB,
        const float* __restrict__ bias, const float* __restrict__ bias2, int Nsplit,
        void* __restrict__ Cbase, long sC,
        int M, int N, int K, float scale,
        float* __restrict__ psumG, float* __restrict__ psqG) {
    constexpr int SMEM_BYTES = (OMODE == 2) ? 34304 : 32768;
    __shared__ __align__(16) char smem[SMEM_BYTES];

    int bxi, byi, bzi;
    swz_xcd(bxi, byi, bzi);

    const int tid  = threadIdx.x;
    const int lane = tid & 63;
    const int w    = tid >> 6;
    const int wm   = w >> 1, wn = w & 1;
    const int bm = byi * 128, bn = bxi * 128;
    const int zz = bzi;

    int zb, kStart, kEnd;
    if constexpr (SPLITK) {
        zb = zz >> 2;
        const int kl = K >> 2;
        kStart = (zz & 3) * kl;
        kEnd = kStart + kl;
    } else {
        zb = zz; kStart = 0; kEnd = K;
    }

    const unsigned short* B = Bbase + (size_t)zb * sB;
    const float* Af = (const float*)Abase_ + (AFP32 ? (size_t)zb * sA : 0);
    const unsigned short* Ah = (const unsigned short*)Abase_ + (AFP32 ? 0 : (size_t)zb * sA);

    const int ldRow = tid >> 2;
    const int ldK   = (tid & 3) * 8;
    const unsigned ldsOff = tid * 16;
    const size_t aOff0 = (size_t)(bm + ldRow) * K + ldK;
    const size_t aOff1 = (size_t)(bm + 64 + ldRow) * K + ldK;
    const size_t bOff0 = (size_t)(bn + ldRow) * K + ldK;
    const size_t bOff1 = (size_t)(bn + 64 + ldRow) * K + ldK;

    f32x4 acc[4][4] = {};
    const int fr = lane & 15;
    const int fh = (lane >> 4) * 16;

    auto bufA = [&](int p) -> char* { return smem + p * 8192; };
    auto bufB = [&](int p) -> char* { return smem + 16384 + p * 8192; };

    auto stageB = [&](int p, int k0) {
        gload16(B + bOff0 + k0, bufB(p) + ldsOff);
        gload16(B + bOff1 + k0, bufB(p) + 4096 + ldsOff);
    };
    auto stageA_g = [&](int p, int k0) {
        gload16(Ah + aOff0 + k0, bufA(p) + ldsOff);
        gload16(Ah + aOff1 + k0, bufA(p) + 4096 + ldsOff);
    };

    float4 na0, na1, na2, na3;   // AFP32 in-flight A tile (single reg set)
    auto loadA_f = [&](int k0) {
        na0 = *(const float4*)(Af + aOff0 + k0); na1 = *(const float4*)(Af + aOff0 + k0 + 4);
        na2 = *(const float4*)(Af + aOff1 + k0); na3 = *(const float4*)(Af + aOff1 + k0 + 4);
    };
    auto writeA_f = [&](int p) {
        *(uint4*)(bufA(p) + ldsOff)        = cvt8(na0, na1);
        *(uint4*)(bufA(p) + 4096 + ldsOff) = cvt8(na2, na3);
    };

    auto compute = [&](int p) {
        const char* smA = bufA(p);
        const char* smB = bufB(p);
        bf16x8 fa[4], fb[4];
#pragma unroll
        for (int m = 0; m < 4; ++m)
            fa[m] = *(const bf16x8*)(smA + (wm * 64 + m * 16 + fr) * 64 + fh);
#pragma unroll
        for (int n = 0; n < 4; ++n)
            fb[n] = *(const bf16x8*)(smB + (wn * 64 + n * 16 + fr) * 64 + fh);
#pragma unroll
        for (int m = 0; m < 4; ++m)
#pragma unroll
            for (int n = 0; n < 4; ++n)
                acc[m][n] = __builtin_amdgcn_mfma_f32_16x16x32_bf16(fa[m], fb[n], acc[m][n], 0, 0, 0);
    };

    const int nt = (kEnd - kStart) >> 5;

    if constexpr (AFP32) {
        loadA_f(kStart);
        stageB(0, kStart);
        writeA_f(0);                                        // implicit wait retires A(0)
        asm volatile("s_waitcnt lgkmcnt(0)" ::: "memory");  // A(0) ds_writes issued+landed
        for (int t = 0; t < nt; ++t) {
            const int p = t & 1;
            const bool more = (t + 1) < nt;
            if (more) {
                loadA_f(kStart + (t + 1) * 32);             // A(t+1) -> regs
                stageB(p ^ 1, kStart + (t + 1) * 32);       // B(t+1) -> LDS
                asm volatile("s_waitcnt vmcnt(6)" ::: "memory");  // retires B(t)
            } else {
                asm volatile("s_waitcnt vmcnt(0)" ::: "memory");
            }
            ACQ();
            compute(p);
            if (more) writeA_f(p ^ 1);   // implicit A(t+1)-reg wait lands AFTER compute
            REL_W();
        }
    } else {
        stageA_g(0, kStart); stageB(0, kStart);
        for (int t = 0; t < nt; ++t) {
            const int p = t & 1;
            const bool more = (t + 1) < nt;
            if (more) {
                stageA_g(p ^ 1, kStart + (t + 1) * 32);
                stageB(p ^ 1, kStart + (t + 1) * 32);
                asm volatile("s_waitcnt vmcnt(4)" ::: "memory");  // retires tile t's 4
            } else {
                asm volatile("s_waitcnt vmcnt(0)" ::: "memory");
            }
            ACQ();
            compute(p);
            REL_N();
        }
    }

    const int r0 = (lane >> 4) * 4;
    const int cc = lane & 15;
    auto getbias = [&](int gcol) -> float {
        if (!bias) return 0.0f;
        return gcol < Nsplit ? bias[gcol] : bias2[gcol - Nsplit];
    };

    if constexpr (OMODE == 0) {
        float* C = (float*)Cbase + (size_t)(SPLITK ? zz : zb) * sC;
#pragma unroll
        for (int n = 0; n < 4; ++n) {
            const int col = bn + wn * 64 + n * 16 + cc;
            const float bv = getbias(col);
#pragma unroll
            for (int m = 0; m < 4; ++m)
#pragma unroll
                for (int j = 0; j < 4; ++j)
                    C[(size_t)(bm + wm * 64 + m * 16 + r0 + j) * N + col] = acc[m][n][j] + bv;
        }
    } else if constexpr (OMODE == 1) {
        unsigned short* C = (unsigned short*)Cbase + (size_t)zb * sC;
#pragma unroll
        for (int n = 0; n < 4; ++n) {
            const int col = bn + wn * 64 + n * 16 + cc;
            const float bv = getbias(col);
#pragma unroll
            for (int m = 0; m < 4; ++m)
#pragma unroll
                for (int j = 0; j < 4; ++j)
                    C[(size_t)(bm + wm * 64 + m * 16 + r0 + j) * N + col] =
                        f2bf(acc[m][n][j] * scale + bv);
        }
    } else if constexpr (OMODE == 2) {
        // LDS transpose then coalesced store to [b][col][token]
        unsigned short* T = (unsigned short*)smem;  // [128 cols][134 rows] bf16
#pragma unroll
        for (int n = 0; n < 4; ++n) {
            const int ccol = wn * 64 + n * 16 + cc;
            const float bv = getbias(bn + ccol);
#pragma unroll
            for (int m = 0; m < 4; ++m)
#pragma unroll
                for (int j = 0; j < 4; ++j)
                    T[ccol * 134 + (wm * 64 + m * 16 + r0 + j)] = f2bf(acc[m][n][j] + bv);
        }
        __syncthreads();
        const int b   = bm >> 11;
        const int bmb = bm & 2047;
        unsigned short* Co = (unsigned short*)Cbase + (size_t)b * N * Ntok;
#pragma unroll
        for (int i = 0; i < 32; ++i) {
            const int d = w * 32 + i;
            const unsigned v = *(const unsigned*)((const char*)smem + d * 268 + lane * 4);
            *(unsigned*)(Co + (size_t)(bn + d) * Ntok + bmb + lane * 2) = v;
        }
    } else {
        // OMODE 3: bf16 out + deterministic per-block column stats
        unsigned short* C = (unsigned short*)Cbase + (size_t)zb * sC;
        float colS[4], colQ[4];
#pragma unroll
        for (int n = 0; n < 4; ++n) {
            const int col = bn + wn * 64 + n * 16 + cc;
            const float bv = getbias(col);
            float s = 0.f, q = 0.f;
#pragma unroll
            for (int m = 0; m < 4; ++m)
#pragma unroll
                for (int j = 0; j < 4; ++j) {
                    const float v = acc[m][n][j] + bv;
                    C[(size_t)(bm + wm * 64 + m * 16 + r0 + j) * N + col] = f2bf(v);
                    s += v; q = fmaf(v, v, q);
                }
            s += __shfl_xor(s, 16); s += __shfl_xor(s, 32);
            q += __shfl_xor(q, 16); q += __shfl_xor(q, 32);
            colS[n] = s; colQ[n] = q;
        }
        float* sums = (float*)smem;   // [2 wm][128 cols]
        float* sqs  = sums + 256;
        if (lane < 16) {
#pragma unroll
            for (int n = 0; n < 4; ++n) {
                sums[wm * 128 + wn * 64 + n * 16 + cc] = colS[n];
                sqs [wm * 128 + wn * 64 + n * 16 + cc] = colQ[n];
            }
        }
        __syncthreads();
        if (tid < 128) {
            const int slot = zb * gridDim.y + byi;
            psumG[(size_t)slot * Cdim + bn + tid] = sums[tid] + sums[128 + tid];
            psqG [(size_t)slot * Cdim + bn + tid] = sqs[tid]  + sqs[128 + tid];
        }
    }
}

// ---------------------------------------------------------------------------
// Split-K reduce: M[b][d1][d2] = bf16( (1/2048) * sum_ks part[b*4+ks][d1][d2] )
// ---------------------------------------------------------------------------
__global__ __launch_bounds__(256) void reduce_mt(const float* __restrict__ part,
                                                 unsigned short* __restrict__ Mo) {
    const int i = blockIdx.x * 256 + threadIdx.x;
    const int e = i * 4;
    const int b = e / (Ddim * Ddim);
    const int r = e - b * (Ddim * Ddim);
    const float* base = part + (size_t)b * 4 * (Ddim * Ddim) + r;
    float4 s = *(const float4*)(base);
    const float4 s1 = *(const float4*)(base + 1 * Ddim * Ddim);
    const float4 s2 = *(const float4*)(base + 2 * Ddim * Ddim);
    const float4 s3 = *(const float4*)(base + 3 * Ddim * Ddim);
    s.x += s1.x + s2.x + s3.x; s.y += s1.y + s2.y + s3.y;
    s.z += s1.z + s2.z + s3.z; s.w += s1.w + s2.w + s3.w;
    constexpr float sc = 1.0f / (float)Ntok;
    union { unsigned short u[4]; uint2 q; } o;
    o.u[0] = f2bf(s.x * sc); o.u[1] = f2bf(s.y * sc);
    o.u[2] = f2bf(s.z * sc); o.u[3] = f2bf(s.w * sc);
    *(uint2*)(Mo + e) = o.q;
}

// ---------------------------------------------------------------------------
__global__ __launch_bounds__(256) void bn_finalize(const float* __restrict__ psum,
                                                   const float* __restrict__ psq,
                                                   const float* __restrict__ gamma,
                                                   const float* __restrict__ beta,
                                                   float* __restrict__ a,
                                                   float* __restrict__ bb) {
    const int c = blockIdx.x * 256 + threadIdx.x;
    if (c >= Cdim) return;
    float s = 0.f, q = 0.f;
    for (int b = 0; b < 128; ++b) { s += psum[(size_t)b * Cdim + c]; q += psq[(size_t)b * Cdim + c]; }
    const float mean = s * (1.0f / (float)Mrows);
    const float var  = fmaf(-mean, mean, q * (1.0f / (float)Mrows));
    const float inv  = rsqrtf(var + 1e-5f);
    const float gsc  = gamma[c] * inv;
    a[c]  = gsc;
    bb[c] = fmaf(-mean, gsc, beta[c]);
}

// out = a[c]*y + bb[c] + x_h ; y bf16, out fp32
__global__ __launch_bounds__(256) void bn_apply(const unsigned short* __restrict__ y,
                                                const float* __restrict__ xh,
                                                const float* __restrict__ a,
                                                const float* __restrict__ bb,
                                                float* __restrict__ outp) {
    const size_t i = (size_t)blockIdx.x * 256 + threadIdx.x;  // uint4 index = 8 bf16
    union { uint4 q; unsigned short u[8]; } v; v.q = ((const uint4*)y)[i];
    const int c8 = (int)(i % (Cdim / 8));
    const float4 A0 = ((const float4*)a)[c8 * 2],  A1 = ((const float4*)a)[c8 * 2 + 1];
    const float4 B0 = ((const float4*)bb)[c8 * 2], B1 = ((const float4*)bb)[c8 * 2 + 1];
    const float4 X0 = ((const float4*)xh)[i * 2],  X1 = ((const float4*)xh)[i * 2 + 1];
    float4 o0, o1;
    o0.x = fmaf(A0.x, bf2f(v.u[0]), B0.x) + X0.x;
    o0.y = fmaf(A0.y, bf2f(v.u[1]), B0.y) + X0.y;
    o0.z = fmaf(A0.z, bf2f(v.u[2]), B0.z) + X0.z;
    o0.w = fmaf(A0.w, bf2f(v.u[3]), B0.w) + X0.w;
    o1.x = fmaf(A1.x, bf2f(v.u[4]), B1.x) + X1.x;
    o1.y = fmaf(A1.y, bf2f(v.u[5]), B1.y) + X1.y;
    o1.z = fmaf(A1.z, bf2f(v.u[6]), B1.z) + X1.z;
    o1.w = fmaf(A1.w, bf2f(v.u[7]), B1.w) + X1.w;
    ((float4*)outp)[i * 2]     = o0;
    ((float4*)outp)[i * 2 + 1] = o1;
}

// ---------------------------------------------------------------------------
extern "C" void kernel_launch(void* const* d_in, const int* in_sizes, int n_in,
                              void* d_out, int out_size, void* d_ws, size_t ws_size,
                              hipStream_t stream) {
    const float* x_h   = (const float*)d_in[0];
    const float* x_l   = (const float*)d_in[1];
    const float* w_g   = (const float*)d_in[2];
    const float* b_g   = (const float*)d_in[3];
    const float* w_th  = (const float*)d_in[4];
    const float* b_th  = (const float*)d_in[5];
    const float* w_ph  = (const float*)d_in[6];
    const float* b_ph  = (const float*)d_in[7];
    const float* w_out = (const float*)d_in[8];
    const float* b_out = (const float*)d_in[9];
    const float* gamma = (const float*)d_in[10];
    const float* beta  = (const float*)d_in[11];
    float* out = (float*)d_out;

    char* p = (char*)d_ws;
    unsigned short* Scr   = (unsigned short*)p; p += (size_t)Mrows * Cdim * 2;  // split-K partials / Y bf16
    unsigned short* Wth16 = (unsigned short*)p; p += 294912 * 2;
    unsigned short* Wpg16 = (unsigned short*)p; p += 2 * 294912 * 2;            // [768][768]: w_phi | w_g
    unsigned short* Wout16= (unsigned short*)p; p += 294912 * 2;
    unsigned short* Tbuf  = (unsigned short*)p; p += (size_t)Mrows * Ddim * 2;  // theta bf16
    unsigned short* PGT   = (unsigned short*)p; p += (size_t)Mrows * Cdim * 2;  // [b][768][2048]: phi^T | g^T
    unsigned short* Mbuf  = (unsigned short*)p; p += (size_t)Bb * Ddim * Ddim * 2;
    unsigned short* QTbuf = (unsigned short*)p; p += (size_t)Bb * Cdim * Ddim * 2;
    float* psum = (float*)p; p += (size_t)128 * Cdim * 4;
    float* psq  = (float*)p; p += (size_t)128 * Cdim * 4;
    float* avec = (float*)p; p += Cdim * 4;
    float* bvec = (float*)p; p += Cdim * 4;
    float* part = (float*)Scr;
    unsigned short* Ybuf = Scr;

    dim3 blk(256);
    const int BIG = 1 << 30;

    cast_w<<<576, blk, 0, stream>>>(w_th, w_ph, w_g, w_out,
                                    Wth16, Wpg16, Wpg16 + 294912, Wout16);
    // theta = x_h * w_theta^T + b_theta (fp32 A inline-cast, bf16 out)
    gemm_bf16<1, false, true><<<dim3(3, 128, 1), blk, 0, stream>>>(
        x_h, 0, Wth16, 0, b_th, nullptr, BIG, Tbuf, 0, Mrows, Ddim, Cdim, 1.0f,
        nullptr, nullptr);
    // [phi | g] = x_l * [w_phi | w_g]^T + bias -> transposed [b][768][2048]
    gemm_bf16<2, false, true><<<dim3(6, 128, 1), blk, 0, stream>>>(
        x_l, 0, Wpg16, 0, b_ph, b_g, Ddim, PGT, 0, Mrows, 2 * Ddim, Cdim, 1.0f,
        nullptr, nullptr);
    // split-K partials: part[b*4+ks][d1][d2] = sum_{n slice} phi^T[d1][n] g^T[d2][n]
    gemm_bf16<0, true, false><<<dim3(3, 3, 32), blk, 0, stream>>>(
        PGT, (long)2 * Ddim * Ntok,
        PGT + (size_t)Ddim * Ntok, (long)2 * Ddim * Ntok, nullptr, nullptr, BIG,
        part, (long)Ddim * Ddim, Ddim, Ddim, Ntok, 1.0f, nullptr, nullptr);
    reduce_mt<<<1152, blk, 0, stream>>>(part, Mbuf);
    // QT[b][c][d1] = sum_d2 w_out[c][d2] * M[b][d1][d2]
    gemm_bf16<1, false, false><<<dim3(3, 6, 8), blk, 0, stream>>>(
        Wout16, 0, Mbuf, (long)Ddim * Ddim, nullptr, nullptr, BIG,
        QTbuf, (long)Cdim * Ddim, Cdim, Ddim, Ddim, 1.0f, nullptr, nullptr);
    // y = theta * QT^T + b_out -> bf16 Ybuf, fused BN column partials
    gemm_bf16<3, false, false><<<dim3(6, 16, 8), blk, 0, stream>>>(
        Tbuf, (long)Ntok * Ddim, QTbuf, (long)Cdim * Ddim, b_out, nullptr, BIG,
        Ybuf, (long)Ntok * Cdim, Ntok, Cdim, Ddim, 1.0f, psum, psq);
    // BN finalize + apply + residual
    bn_finalize<<<dim3(3), blk, 0, stream>>>(psum, psq, gamma, beta, avec, bvec);
    bn_apply<<<dim3(6144), blk, 0, stream>>>(Ybuf, x_h, avec, bvec, out);
}